// Round 3
// baseline (3156.060 us; speedup 1.0000x reference)
//
#include <hip/hip_runtime.h>
#include <hip/hip_bf16.h>

#define T_LEN 2048
#define BATCH 32
#define HDIM 256
#define H3 768
#define EMBD 63
#define NSING 1024

typedef _Float16 half2_t __attribute__((ext_vector_type(2)));

__device__ __forceinline__ float fdot2u(unsigned int a, unsigned int b, float c) {
#if __has_builtin(__builtin_amdgcn_fdot2)
  return __builtin_amdgcn_fdot2(__builtin_bit_cast(half2_t, a),
                                __builtin_bit_cast(half2_t, b), c, false);
#else
  half2_t ha = __builtin_bit_cast(half2_t, a);
  half2_t hb = __builtin_bit_cast(half2_t, b);
  return c + (float)ha.x * (float)hb.x + (float)ha.y * (float)hb.y;
#endif
}

// P[s][j] = bi[j] + sum_e embed[s,e] * Wi[(1+e),j]   (input-gate GEMM folded per singer)
__global__ __launch_bounds__(768) void precompute_P(
    const float* __restrict__ embed, const float* __restrict__ Wi,
    const float* __restrict__ bi, float* __restrict__ P) {
  const int s = blockIdx.x;
  const int j = threadIdx.x;
  float acc = bi[j];
  const float* er = embed + s * EMBD;
#pragma unroll
  for (int e = 0; e < EMBD; e++) acc += er[e] * Wi[(e + 1) * H3 + j];
  P[s * H3 + j] = acc;
}

// Pack Wh (f32 [256][768]) into f16-pair dwords: Whp[(dir*128+k)*768+j] =
// pack(Wh[2k][j], Wh[2k+1][j]).  Scan then loads 128 coalesced dwords/thread.
__global__ __launch_bounds__(768) void pack_Wh(
    const float* __restrict__ Wh_f, const float* __restrict__ Wh_b,
    unsigned int* __restrict__ Whp) {
  const int k = blockIdx.x & 127;
  const int d = blockIdx.x >> 7;
  const int j = threadIdx.x;
  const float* Wh = d ? Wh_b : Wh_f;
  half2_t hp;
  hp.x = (_Float16)Wh[(2 * k) * H3 + j];
  hp.y = (_Float16)Wh[(2 * k + 1) * H3 + j];
  Whp[((size_t)(d * 128 + k)) * H3 + j] = __builtin_bit_cast(unsigned int, hp);
}

// One workgroup per (dir, batch). 768 threads; thread j owns Wh column j in
// 128 packed-f16 VGPRs. h kept in LDS as packed f16 (broadcast reads).
//
// Register strategy (rounds 1-2 post-mortem): the allocator kept reporting
// 80-84 VGPRs because the 128 weight loads are INVARIANT loads -> it
// rematerializes them (re-loads from L2 every timestep) instead of keeping
// them live. The empty asm below makes each w[k]'s reaching def an opaque
// inline-asm output, which LLVM cannot rematerialize, forcing true register
// residency. waves_per_eu(3,3) pins the budget at 512/3 = 170 VGPRs
// (12 waves = 3/SIMD is all this 64-block grid can use anyway).
__global__ __attribute__((amdgpu_flat_work_group_size(768, 768),
                          amdgpu_waves_per_eu(3, 3))) void gru_scan(
    const float* __restrict__ dur, const int* __restrict__ sid,
    const unsigned int* __restrict__ Whp,
    const float* __restrict__ Wi_f, const float* __restrict__ Wi_b,
    const float* __restrict__ bhn_f, const float* __restrict__ bhn_b,
    const float* __restrict__ Wd,
    const float* __restrict__ Pf, const float* __restrict__ Pb,
    float* __restrict__ partial) {
  const int b = blockIdx.x & 31;
  const int dir = blockIdx.x >> 5;
  const int j = threadIdx.x;

  const float* __restrict__ Wi = dir ? Wi_b : Wi_f;
  const float* __restrict__ P = dir ? Pb : Pf;
  const float* __restrict__ bhn = dir ? bhn_b : bhn_f;

  __shared__ __align__(16) unsigned int h2buf[HDIM / 2];  // packed f16 h (128 dwords)
  __shared__ float glds[H3];  // [0:256) z, [256:512) hn+bhn, [512:768) inn
  __shared__ float red[4];

  // Load packed Wh column j: 128 coalesced dword loads, persistent in VGPRs.
  unsigned int w[128];
  {
    const unsigned int* wrow = Whp + (size_t)dir * 128 * H3 + j;
#pragma unroll
    for (int k = 0; k < 128; k++) w[k] = wrow[k * H3];
  }
  // Anti-rematerialization fence: each w[k] is now defined by an opaque asm
  // (zero instructions emitted) -> must stay in a VGPR across the scan.
#pragma unroll
  for (int k = 0; k < 128; k++) asm volatile("" : "+v"(w[k]));

  const float wi0 = Wi[j];                                   // duration weight
  const float wd = (j < HDIM) ? Wd[dir * HDIM + j] : 0.f;    // output head slice
  const float bhnj = (j >= 2 * HDIM) ? bhn[j - 2 * HDIM] : 0.f;

  if (j < HDIM / 2) h2buf[j] = 0u;
  float h_prev = 0.f;

  const float* durb = dur + b * T_LEN;
  const int* sidb = sid + b * T_LEN;
  float* pout = partial + ((size_t)dir * BATCH + b) * T_LEN;

  // 1-deep prefetch of the P row (gather latency hides under the dot chain).
  const int tt0 = dir ? (T_LEN - 1) : 0;
  float p_c = P[sidb[tt0] * H3 + j];
  __syncthreads();

  for (int t = 0; t < T_LEN; t++) {
    const int tt = dir ? (T_LEN - 1 - t) : t;
    const int tn = (t + 1 < T_LEN) ? (t + 1) : (T_LEN - 1);
    const int ttn = dir ? (T_LEN - 1 - tn) : tn;
    const float p_nx = P[sidb[ttn] * H3 + j];  // issued before the dot chain
    const float d_c = durb[tt];                // uniform scalar load

    // gh[j] = sum_k h[k] * Wh[k][j]  -- 128 x v_dot2_f32_f16
    float a0 = 0.f, a1 = 0.f, a2 = 0.f, a3 = 0.f;
#pragma unroll
    for (int k = 0; k < 32; k++) {
      uint4 hv = ((const uint4*)h2buf)[k];
      a0 = fdot2u(hv.x, w[4 * k + 0], a0);
      a1 = fdot2u(hv.y, w[4 * k + 1], a1);
      a2 = fdot2u(hv.z, w[4 * k + 2], a2);
      a3 = fdot2u(hv.w, w[4 * k + 3], a3);
    }
    const float gh = (a0 + a1) + (a2 + a3);
    const float gi = p_c + d_c * wi0;  // input gate contribution

    if (j >= 2 * HDIM) {
      glds[j - HDIM] = gh + bhnj;  // hn + bhn
      glds[j] = gi;                // inn (kept separate: r multiplies only hn+bhn)
    } else if (j >= HDIM) {
      const float x = gh + gi;
      glds[j - HDIM] = 1.f / (1.f + __expf(-x));  // z computed by owning thread
    }
    __syncthreads();

    if (j < HDIM) {
      const float x = gh + gi;
      const float r = 1.f / (1.f + __expf(-x));
      const float z = glds[j];
      const float nin = glds[2 * HDIM + j] + r * glds[HDIM + j];
      const float n = 1.f - 2.f / (1.f + __expf(2.f * nin));  // tanh(nin), overflow-safe
      const float h_new = n + z * (h_prev - n);
      h_prev = h_new;
      ((unsigned short*)h2buf)[j] =
          __builtin_bit_cast(unsigned short, (_Float16)h_new);
      // fused output head: pd = h_new * Wd[j], wave-reduce
      float pd = h_new * wd;
#pragma unroll
      for (int off = 32; off >= 1; off >>= 1) pd += __shfl_down(pd, off, 64);
      if ((j & 63) == 0) red[j >> 6] = pd;
    }
    __syncthreads();
    if (j == 0)
      pout[tt] = (red[0] + red[1]) + (red[2] + red[3]);

    p_c = p_nx;
  }
}

__global__ void combine(const float* __restrict__ pf, const float* __restrict__ pb,
                        const float* __restrict__ bd, float* __restrict__ out) {
  const int i = blockIdx.x * blockDim.x + threadIdx.x;
  out[i] = pf[i] + pb[i] + bd[0];
}

extern "C" void kernel_launch(void* const* d_in, const int* in_sizes, int n_in,
                              void* d_out, int out_size, void* d_ws, size_t ws_size,
                              hipStream_t stream) {
  const float* dur = (const float*)d_in[0];
  const int* sid = (const int*)d_in[1];
  const float* embed = (const float*)d_in[2];
  const float* Wi_f = (const float*)d_in[3];
  const float* Wh_f = (const float*)d_in[4];
  const float* bi_f = (const float*)d_in[5];
  const float* bhn_f = (const float*)d_in[6];
  const float* Wi_b = (const float*)d_in[7];
  const float* Wh_b = (const float*)d_in[8];
  const float* bi_b = (const float*)d_in[9];
  const float* bhn_b = (const float*)d_in[10];
  const float* Wd = (const float*)d_in[11];
  const float* bd = (const float*)d_in[12];
  float* out = (float*)d_out;

  // ws layout (floats): [0,65536) fwd partial, [65536,131072) bwd partial,
  // then Pf (1024*768), then Pb (1024*768), then Whp (2*128*768 dwords).
  float* ws = (float*)d_ws;
  float* pf = ws;
  float* pb = ws + 65536;
  float* Pf = ws + 131072;
  float* Pb = Pf + NSING * H3;
  unsigned int* Whp = (unsigned int*)(Pb + NSING * H3);

  hipLaunchKernelGGL(precompute_P, dim3(NSING), dim3(H3), 0, stream, embed, Wi_f, bi_f, Pf);
  hipLaunchKernelGGL(precompute_P, dim3(NSING), dim3(H3), 0, stream, embed, Wi_b, bi_b, Pb);
  hipLaunchKernelGGL(pack_Wh, dim3(256), dim3(H3), 0, stream, Wh_f, Wh_b, Whp);
  hipLaunchKernelGGL(gru_scan, dim3(64), dim3(H3), 0, stream,
                     dur, sid, Whp, Wi_f, Wi_b, bhn_f, bhn_b, Wd, Pf, Pb, ws);
  hipLaunchKernelGGL(combine, dim3(out_size / 256), dim3(256), 0, stream, pf, pb, bd, out);
}

// Round 5
// 2536.827 us; speedup vs baseline: 1.2441x; 1.2441x over previous
//
#include <hip/hip_runtime.h>
#include <hip/hip_bf16.h>

#define T_LEN 2048
#define BATCH 32
#define HDIM 256
#define H3 768
#define EMBD 63
#define NSING 1024

typedef _Float16 half2_t __attribute__((ext_vector_type(2)));

__device__ __forceinline__ float fdot2u(unsigned int a, unsigned int b, float c) {
  return __builtin_amdgcn_fdot2(__builtin_bit_cast(half2_t, a),
                                __builtin_bit_cast(half2_t, b), c, false);
}

// x += dpp_moved(x); ctrl must be a literal. bound_ctrl=true -> 0-fill.
#define DPP_ADD(x, ctrl)                                                      \
  (x) += __builtin_bit_cast(                                                  \
      float, __builtin_amdgcn_update_dpp(                                     \
                 0, __builtin_bit_cast(int, (x)), (ctrl), 0xf, 0xf, true))

// P2[g][s][jj] (f16) = bi[g*256+jj] + sum_e embed[s,e] * Wi[(1+e)][g*256+jj]
__global__ __launch_bounds__(768) void precompute_P(
    const float* __restrict__ embed, const float* __restrict__ Wi,
    const float* __restrict__ bi, _Float16* __restrict__ P2) {
  const int s = blockIdx.x;
  const int jg = threadIdx.x;  // 0..767
  const int g = jg >> 8, jj = jg & 255;
  float acc = bi[jg];
  const float* er = embed + s * EMBD;
#pragma unroll
  for (int e = 0; e < EMBD; e++) acc += er[e] * Wi[(e + 1) * H3 + jg];
  P2[((size_t)g * NSING + s) * HDIM + jj] = (_Float16)acc;
}

// Whp[(((d*2+half)*64 + k2)*3 + g)*256 + j] =
//   pack_f16(Wh_d[half*128 + 2*k2][g*256+j], Wh_d[half*128 + 2*k2 + 1][g*256+j])
__global__ __launch_bounds__(256) void pack_Wh(
    const float* __restrict__ Wh_f, const float* __restrict__ Wh_b,
    unsigned int* __restrict__ Whp) {
  const int bid = blockIdx.x;  // = d*384 + half*192 + k2*3 + g  (768 blocks)
  const int j = threadIdx.x;
  const int g = bid % 3;
  const int k2 = (bid / 3) & 63;
  const int half = (bid / 192) & 1;
  const int d = bid / 384;
  const float* Wh = d ? Wh_b : Wh_f;
  const int r0 = half * 128 + 2 * k2;
  half2_t hp;
  hp.x = (_Float16)Wh[r0 * H3 + g * 256 + j];
  hp.y = (_Float16)Wh[(r0 + 1) * H3 + g * 256 + j];
  Whp[(size_t)bid * 256 + j] = __builtin_bit_cast(unsigned int, hp);
}

// One workgroup per (dir, batch): 512 threads = 8 waves = 2 waves/SIMD.
// Thread (j = tid&255, half = tid>>8) owns the K-half [half*128, half*128+128)
// of ALL THREE gate columns (r,z,n) for output j: 192 packed-f16 dwords.
// Why this shape (rounds 1-3 post-mortem): 236-reg pressure fits the natural
// 256-VGPR/2-wave tier, so the allocator has no incentive to home w[] in
// AGPRs (the accvgpr-copy tax that ate rounds 1-3). Each thread reads only
// its h-half from LDS (broadcast), reused across 3 gates -> 128 b128/CU/step
// instead of 384. Gate math is thread-local; only a 3-float partial merge
// crosses the half boundary.
__global__ __attribute__((amdgpu_flat_work_group_size(512, 512),
                          amdgpu_waves_per_eu(2, 2))) void gru_scan(
    const float* __restrict__ dur, const int* __restrict__ sid,
    const unsigned int* __restrict__ Whp,
    const float* __restrict__ Wi_f, const float* __restrict__ Wi_b,
    const float* __restrict__ bhn_f, const float* __restrict__ bhn_b,
    const float* __restrict__ Wd,
    const _Float16* __restrict__ P2,  // [dir][g][s][256] f16
    float* __restrict__ pred) {       // [dir][b][t][4]
  const int b = blockIdx.x & 31;
  const int dir = blockIdx.x >> 5;
  const int tid = threadIdx.x;
  const int j = tid & 255;
  const int half = tid >> 8;

  const float* __restrict__ Wi = dir ? Wi_b : Wi_f;
  const float* __restrict__ bhn = dir ? bhn_b : bhn_f;
  const _Float16* __restrict__ Pd = P2 + (size_t)dir * 3 * NSING * HDIM;

  __shared__ __align__(16) unsigned int h2buf[2][128];  // packed-f16 h, dbuf
  __shared__ float pbuf[3][256];                        // half=1 partials
  
  // Load my 192 weight dwords (coalesced: stride-256 rows, j within row).
  unsigned int w[192];
  {
    const unsigned int* wp = Whp + ((size_t)(dir * 2 + half)) * 192 * 256 + j;
#pragma unroll
    for (int i = 0; i < 192; i++) w[i] = wp[i * 256];
  }
#pragma unroll
  for (int i = 0; i < 192; i++) asm volatile("" : "+v"(w[i]));

  const float wi0r = Wi[j], wi0z = Wi[HDIM + j], wi0n = Wi[2 * HDIM + j];
  const float wd = Wd[dir * HDIM + j];
  const float bhnj = bhn[j];

  if (tid < 128) h2buf[0][tid] = 0u;
  float h_prev = 0.f;

  const float* durb = dur + b * T_LEN;
  const int* sidb = sid + b * T_LEN;
  float* predb = pred + ((size_t)(dir * BATCH + b)) * T_LEN * 4;

  // 1-deep P prefetch (used only by half=0).
  float p_r = 0.f, p_z = 0.f, p_n = 0.f;
  if (!half) {
    const int s0 = sidb[dir ? (T_LEN - 1) : 0];
    p_r = (float)Pd[(0 * NSING + s0) * HDIM + j];
    p_z = (float)Pd[(1 * NSING + s0) * HDIM + j];
    p_n = (float)Pd[(2 * NSING + s0) * HDIM + j];
  }
  __syncthreads();

#pragma unroll 1
  for (int t = 0; t < T_LEN; t++) {
    const int cur = t & 1;
    const int tt = dir ? (T_LEN - 1 - t) : t;
    const int tn = (t + 1 < T_LEN) ? (t + 1) : (T_LEN - 1);
    float q_r, q_z, q_n;
    if (!half) {
      const int s1 = sidb[dir ? (T_LEN - 1 - tn) : tn];
      q_r = (float)Pd[(0 * NSING + s1) * HDIM + j];
      q_z = (float)Pd[(1 * NSING + s1) * HDIM + j];
      q_n = (float)Pd[(2 * NSING + s1) * HDIM + j];
    }
    const float d_c = durb[tt];

    // partial dots over my K-half: 16 broadcast b128 reads, 192 dot2.
    const uint4* hv4 = (const uint4*)&h2buf[cur][half * 64];
    float ar = 0, az = 0, an = 0, ar2 = 0, az2 = 0, an2 = 0;
#pragma unroll
    for (int kk = 0; kk < 16; kk++) {
      const uint4 hv = hv4[kk];
      const int bi_ = kk * 12;
      ar = fdot2u(hv.x, w[bi_ + 0], ar);
      az = fdot2u(hv.x, w[bi_ + 1], az);
      an = fdot2u(hv.x, w[bi_ + 2], an);
      ar2 = fdot2u(hv.y, w[bi_ + 3], ar2);
      az2 = fdot2u(hv.y, w[bi_ + 4], az2);
      an2 = fdot2u(hv.y, w[bi_ + 5], an2);
      ar = fdot2u(hv.z, w[bi_ + 6], ar);
      az = fdot2u(hv.z, w[bi_ + 7], az);
      an = fdot2u(hv.z, w[bi_ + 8], an);
      ar2 = fdot2u(hv.w, w[bi_ + 9], ar2);
      az2 = fdot2u(hv.w, w[bi_ + 10], az2);
      an2 = fdot2u(hv.w, w[bi_ + 11], an2);
    }
    const float sr = ar + ar2, sz = az + az2, sv = an + an2;

    if (half) {
      pbuf[0][j] = sr;
      pbuf[1][j] = sz;
      pbuf[2][j] = sv;
    }
    __syncthreads();  // B1: partials visible

    if (!half) {
      const float ghr = sr + pbuf[0][j];
      const float ghz = sz + pbuf[1][j];
      const float ghn = sv + pbuf[2][j];
      const float r = 1.f / (1.f + __expf(-(p_r + d_c * wi0r + ghr)));
      const float z = 1.f / (1.f + __expf(-(p_z + d_c * wi0z + ghz)));
      const float nin = p_n + d_c * wi0n + r * (ghn + bhnj);
      const float n = 1.f - 2.f / (1.f + __expf(2.f * nin));  // tanh, safe
      const float h_new = n + z * (h_prev - n);
      h_prev = h_new;
      ((unsigned short*)&h2buf[cur ^ 1][0])[j] =
          __builtin_bit_cast(unsigned short, (_Float16)h_new);
      // fused output head: wave-sum via DPP (VALU pipe, keeps DS pipe free)
      float pd = h_new * wd;
      DPP_ADD(pd, 0x111);  // row_shr:1
      DPP_ADD(pd, 0x112);  // row_shr:2
      DPP_ADD(pd, 0x114);  // row_shr:4
      DPP_ADD(pd, 0x118);  // row_shr:8  -> lane15 of each row = row sum
      DPP_ADD(pd, 0x142);  // row_bcast:15 -> lane31 = rows01, lane63 = rows23
      DPP_ADD(pd, 0x143);  // row_bcast:31 -> lane63 = wave total
      if ((tid & 63) == 63) predb[tt * 4 + (tid >> 6)] = pd;
      p_r = q_r; p_z = q_z; p_n = q_n;
    }
    __syncthreads();  // B2: h2buf[cur^1] + pbuf reuse safe
  }
}

__global__ __launch_bounds__(256) void combine(
    const float* __restrict__ pf, const float* __restrict__ pb,
    const float* __restrict__ bd, float* __restrict__ out) {
  const int i = blockIdx.x * 256 + threadIdx.x;  // i = b*2048 + t
  const float4 a = ((const float4*)pf)[i];
  const float4 c = ((const float4*)pb)[i];
  out[i] = (a.x + a.y + a.z + a.w) + (c.x + c.y + c.z + c.w) + bd[0];
}

extern "C" void kernel_launch(void* const* d_in, const int* in_sizes, int n_in,
                              void* d_out, int out_size, void* d_ws, size_t ws_size,
                              hipStream_t stream) {
  const float* dur = (const float*)d_in[0];
  const int* sid = (const int*)d_in[1];
  const float* embed = (const float*)d_in[2];
  const float* Wi_f = (const float*)d_in[3];
  const float* Wh_f = (const float*)d_in[4];
  const float* bi_f = (const float*)d_in[5];
  const float* bhn_f = (const float*)d_in[6];
  const float* Wi_b = (const float*)d_in[7];
  const float* Wh_b = (const float*)d_in[8];
  const float* bi_b = (const float*)d_in[9];
  const float* bhn_b = (const float*)d_in[10];
  const float* Wd = (const float*)d_in[11];
  const float* bd = (const float*)d_in[12];
  float* out = (float*)d_out;

  // ws (floats): pred 2*32*2048*4 = 524288 | P2 (f16) 2*3*1024*256 halves
  // = 786432 float-equiv | Whp 2*2*64*3*256 = 196608 dwords.  ~5.75 MB.
  float* ws = (float*)d_ws;
  float* pred = ws;
  _Float16* P2 = (_Float16*)(ws + 524288);
  unsigned int* Whp = (unsigned int*)(ws + 524288 + 786432);

  hipLaunchKernelGGL(precompute_P, dim3(NSING), dim3(H3), 0, stream,
                     embed, Wi_f, bi_f, P2);
  hipLaunchKernelGGL(precompute_P, dim3(NSING), dim3(H3), 0, stream,
                     embed, Wi_b, bi_b, P2 + (size_t)3 * NSING * HDIM);
  hipLaunchKernelGGL(pack_Wh, dim3(768), dim3(256), 0, stream, Wh_f, Wh_b, Whp);
  hipLaunchKernelGGL(gru_scan, dim3(64), dim3(512), 0, stream,
                     dur, sid, Whp, Wi_f, Wi_b, bhn_f, bhn_b, Wd, P2, pred);
  hipLaunchKernelGGL(combine, dim3(256), dim3(256), 0, stream,
                     pred, pred + 262144, bd, out);
}